// Round 2
// baseline (836.396 us; speedup 1.0000x reference)
//
#include <hip/hip_runtime.h>
#include <hip/hip_bf16.h>
#include <math.h>

// Problem constants
#define BB 16
#define NN 1024
#define FF 128
#define NCG 64
#define NCONV 3

// ---- output layout (floats) ----
static const size_t O_M     = 0;
static const size_t O_MN    = (size_t)BB*NN*NCG;              // 1048576
static const size_t O_H     = O_MN  + (size_t)BB*NN*NCG;      // 2097152
static const size_t O_HH    = O_H   + (size_t)BB*NN*FF;       // 4194304
static const size_t O_ADJ   = O_HH  + (size_t)BB*NCG*FF;      // 4325376
static const size_t O_CGXYZ = O_ADJ + (size_t)BB*NN*NN;       // 21102592
static const size_t O_CGADJ = O_CGXYZ + (size_t)BB*NCG*3;     // 21105664
static const size_t O_KN    = O_CGADJ + (size_t)BB*NCG*NCG;   // 21171200

// f64 scratch inside the adj output region (written last): 40MB < 64MB
static const size_t S_H64   = 0;                               // [B*N*F] doubles
static const size_t S_T64   = (size_t)BB*NN*FF;                // [B*N*F] doubles
static const size_t S_LM64  = S_T64 + (size_t)BB*NN*FF;        // [B*N*NCG] doubles (logits->M)

// ---- ws layout (doubles) ----
static const size_t W_INVD  = 0;                               // invdeg [B*N] doubles
static const size_t W_COLS  = (size_t)BB*NN;                   // colsum [B*NCG] doubles
static const size_t W_CG    = W_COLS + (size_t)BB*NCG;         // cg64 [B*NCG*3] doubles
static const size_t W_DEG   = W_CG + (size_t)BB*NCG*3;         // degcnt ints (reinterpreted)

// ---------------- init ----------------
__global__ void k_zero_small(int* degcnt, double* colsum) {
    int i = blockIdx.x * blockDim.x + threadIdx.x;
    if (i < BB*NN) degcnt[i] = 0;
    if (i < BB*NCG) colsum[i] = 0.0;
}

__global__ void k_deg(const int* __restrict__ bonds, int nb, int* degcnt) {
    int i = blockIdx.x * blockDim.x + threadIdx.x;
    if (i >= nb) return;
    int b = bonds[i*3+0], s = bonds[i*3+1], t = bonds[i*3+2];
    atomicAdd(&degcnt[b*NN + s], 1);
    atomicAdd(&degcnt[b*NN + t], 1);
}

__global__ void k_invdeg(const int* __restrict__ degcnt, double* invdeg) {
    int i = blockIdx.x * blockDim.x + threadIdx.x;
    if (i >= BB*NN) return;
    int d = degcnt[i];
    invdeg[i] = d > 0 ? 1.0 / (double)d : 0.0;
}

__global__ void k_cgadj(float* cgadj) {
    int idx = blockIdx.x * blockDim.x + threadIdx.x;
    if (idx >= BB*NCG*NCG) return;
    int i = (idx / NCG) % NCG, j = idx % NCG;
    cgadj[idx] = (i == j) ? 0.f : 1.f;
}

__global__ void k_emb64(const int* __restrict__ atoms, const float* __restrict__ emb,
                        double* __restrict__ h) {
    int idx = blockIdx.x * blockDim.x + threadIdx.x;   // (B*N)*32 float4 groups
    if (idx >= BB*NN*(FF/4)) return;
    int n = idx / (FF/4), f4 = idx % (FF/4);
    int a = atoms[n];
    const float4 v = *reinterpret_cast<const float4*>(&emb[(size_t)a*FF + f4*4]);
    double* hp = &h[(size_t)n*FF + f4*4];
    hp[0] = (double)v.x; hp[1] = (double)v.y; hp[2] = (double)v.z; hp[3] = (double)v.w;
}

// ---------------- f64 GEMM: out = act(in @ W + b), K=128, rows tiled by 32 ----------------
template<int COUT, bool TANH>
__global__ __launch_bounds__(256) void k_gemm64(const double* __restrict__ in,
                                                const float* __restrict__ W,
                                                const float* __restrict__ bias,
                                                double* __restrict__ out) {
    constexpr int K = 128;
    constexpr int ROWS = 32;
    constexpr int KC = 16;
    constexpr int CT = COUT / 4;     // 32 or 16
    constexpr int RT = 256 / CT;     // 8 or 16
    constexpr int RPT = ROWS / RT;   // 4 or 2
    __shared__ double As[ROWS * K];  // 32 KB
    __shared__ double Ws[KC * COUT]; // 16 or 8 KB
    const int tid = threadIdx.x;
    const size_t row0 = (size_t)blockIdx.x * ROWS;

    {   // stage A: 32x128 doubles = 2048 double2
        const double2* in2 = reinterpret_cast<const double2*>(in + row0 * K);
        double2* As2 = reinterpret_cast<double2*>(As);
        #pragma unroll
        for (int i = 0; i < 8; ++i) As2[tid + i*256] = in2[tid + i*256];
    }

    const int tc = tid % CT, tr = tid / CT;
    const int c0 = tc * 4, r0 = tr * RPT;
    double acc[RPT][4];
    #pragma unroll
    for (int i = 0; i < RPT; ++i)
        #pragma unroll
        for (int j = 0; j < 4; ++j) acc[i][j] = 0.0;

    for (int kc = 0; kc < K; kc += KC) {
        __syncthreads();   // A ready (first iter); Ws reads of prev chunk done
        {   // stage W chunk (f32 -> f64): KC*COUT floats
            constexpr int NF4 = KC * COUT / 4;   // 512 (COUT=128) or 256 (COUT=64)
            const float4* Wg = reinterpret_cast<const float4*>(W + (size_t)kc * COUT);
            #pragma unroll
            for (int i = 0; i < NF4/256; ++i) {
                int idx = tid + i*256;
                float4 w = Wg[idx];
                Ws[idx*4+0] = (double)w.x;
                Ws[idx*4+1] = (double)w.y;
                Ws[idx*4+2] = (double)w.z;
                Ws[idx*4+3] = (double)w.w;
            }
        }
        __syncthreads();
        #pragma unroll
        for (int kk = 0; kk < KC; ++kk) {
            double a[RPT];
            #pragma unroll
            for (int i = 0; i < RPT; ++i) a[i] = As[(r0+i)*K + kc + kk];
            const double w0 = Ws[kk*COUT + c0 + 0];
            const double w1 = Ws[kk*COUT + c0 + 1];
            const double w2 = Ws[kk*COUT + c0 + 2];
            const double w3 = Ws[kk*COUT + c0 + 3];
            #pragma unroll
            for (int i = 0; i < RPT; ++i) {
                acc[i][0] += a[i]*w0;
                acc[i][1] += a[i]*w1;
                acc[i][2] += a[i]*w2;
                acc[i][3] += a[i]*w3;
            }
        }
    }

    #pragma unroll
    for (int i = 0; i < RPT; ++i) {
        #pragma unroll
        for (int j = 0; j < 4; ++j) {
            double v = acc[i][j] + (double)bias[c0+j];
            if (TANH) v = tanh(v);
            out[(row0 + r0 + i) * COUT + c0 + j] = v;
        }
    }
}

// ---------------- graph-conv scatter: h[b,t,:] += ch[b,s,:]*invdeg[t] (sym) ----------------
__global__ void k_scatter64(const double* __restrict__ ch, const double* __restrict__ invdeg,
                            const int* __restrict__ bonds, int nb, double* h) {
    int idx = blockIdx.x * blockDim.x + threadIdx.x;
    if (idx >= nb * (FF/4)) return;
    int bond = idx / (FF/4), f4 = idx % (FF/4);
    int b = bonds[bond*3+0], s = bonds[bond*3+1], t = bonds[bond*3+2];
    size_t base = (size_t)b * NN * FF;
    const double* cs = &ch[base + (size_t)s*FF + f4*4];
    const double* ct = &ch[base + (size_t)t*FF + f4*4];
    double ws = invdeg[b*NN + s], wt = invdeg[b*NN + t];
    double* hs = &h[base + (size_t)s*FF + f4*4];
    double* ht = &h[base + (size_t)t*FF + f4*4];
    #pragma unroll
    for (int q = 0; q < 4; ++q) atomicAdd(ht+q, cs[q]*wt);
    #pragma unroll
    for (int q = 0; q < 4; ++q) atomicAdd(hs+q, ct[q]*ws);
}

// ---------------- gumbel softmax (f64, in-place logits->M) ----------------
__global__ void k_softmax64(double* __restrict__ lm, const float* __restrict__ gum,
                            const float* __restrict__ tau_p, float* __restrict__ M_out,
                            double* __restrict__ colsum) {
    int row = blockIdx.x * 4 + threadIdx.x / 64;   // B*N rows
    int lane = threadIdx.x & 63;
    double tau = (double)(*tau_p);
    double u = (double)gum[(size_t)row*NCG + lane];
    double g = -log(-log(u));
    double v = (lm[(size_t)row*NCG + lane] + g) / tau;
    double m = v;
    #pragma unroll
    for (int off = 32; off; off >>= 1) m = fmax(m, __shfl_xor(m, off));
    double e = exp(v - m);
    double s = e;
    #pragma unroll
    for (int off = 32; off; off >>= 1) s += __shfl_xor(s, off);
    double mv = e / s;
    lm[(size_t)row*NCG + lane] = mv;
    M_out[(size_t)row*NCG + lane] = (float)mv;
    atomicAdd(&colsum[(row >> 10) * NCG + lane], mv);
}

__global__ void k_mnorm_out(const double* __restrict__ M, const double* __restrict__ colsum,
                            float* __restrict__ Mn) {
    size_t i = (size_t)blockIdx.x * blockDim.x + threadIdx.x;
    if (i >= (size_t)BB*NN*NCG) return;
    size_t b = i >> 16;
    int j = (int)(i & 63);
    Mn[i] = (float)(M[i] / colsum[b*NCG + j]);
}

__global__ void k_hout(const double* __restrict__ h64, float* __restrict__ h) {
    size_t i = (size_t)blockIdx.x * blockDim.x + threadIdx.x;
    if (i >= (size_t)BB*NN*FF) return;
    h[i] = (float)h64[i];
}

// ---------------- H[b,j,f] = (1/colsum[j]) * sum_n M[b,n,j] h[b,n,f] ----------------
__global__ void k_H64(const double* __restrict__ M, const double* __restrict__ colsum,
                      const double* __restrict__ h, float* __restrict__ H) {
    int b = blockIdx.x / 8, jt = blockIdx.x % 8;
    int f = threadIdx.x % FF, jg = threadIdx.x / FF;
    int j0 = jt*8 + jg*4;
    double acc[4] = {0.0, 0.0, 0.0, 0.0};
    const double* Mb = M + (size_t)b*NN*NCG;
    const double* hb = h + (size_t)b*NN*FF;
    for (int n = 0; n < NN; ++n) {
        double hv = hb[(size_t)n*FF + f];
        #pragma unroll
        for (int i = 0; i < 4; ++i) acc[i] += Mb[(size_t)n*NCG + j0 + i] * hv;
    }
    #pragma unroll
    for (int i = 0; i < 4; ++i)
        H[(size_t)b*NCG*FF + (size_t)(j0+i)*FF + f] = (float)(acc[i] / colsum[b*NCG + j0 + i]);
}

// ---------------- cg_xyz[b,j,d] = (1/colsum[j]) * sum_i xyz[b,i,d] M[b,i,j] ----------------
__global__ void k_cgxyz64(const double* __restrict__ M, const double* __restrict__ colsum,
                          const float* __restrict__ xyz, double* __restrict__ cg64,
                          float* __restrict__ cg) {
    int b = blockIdx.x;
    int tid = threadIdx.x;
    if (tid >= NCG*3) return;
    int j = tid / 3, d = tid % 3;
    double acc = 0.0;
    const double* Mb = M + (size_t)b*NN*NCG;
    const float* xb = xyz + (size_t)b*NN*3;
    for (int i = 0; i < NN; ++i)
        acc += (double)xb[i*3 + d] * Mb[(size_t)i*NCG + j];
    double v = acc / colsum[b*NCG + j];
    cg64[(size_t)b*NCG*3 + j*3 + d] = v;
    cg[(size_t)b*NCG*3 + j*3 + d] = (float)v;
}

// ---------------- dist + argsort (f64) ----------------
__global__ void k_knbrs64(const double* __restrict__ cg, float* __restrict__ kn) {
    __shared__ double cs[NCG*3];
    __shared__ double ds[NCG][NCG+1];
    __shared__ int    is[NCG][NCG+1];
    int b = blockIdx.x;
    int i = threadIdx.x;   // 64 threads
    for (int t = i; t < NCG*3; t += 64) cs[t] = cg[(size_t)b*NCG*3 + t];
    __syncthreads();
    double xi = cs[i*3+0], yi = cs[i*3+1], zi = cs[i*3+2];
    for (int j = 0; j < NCG; ++j) {
        double dx = xi - cs[j*3+0], dy = yi - cs[j*3+1], dz = zi - cs[j*3+2];
        ds[i][j] = sqrt(dx*dx + dy*dy + dz*dz + 0.001);
        is[i][j] = j;
    }
    for (int p = 0; p < NCG; ++p) {
        int best = p;
        double bv = ds[i][p];
        for (int q = p+1; q < NCG; ++q) {
            double v = ds[i][q];
            if (v < bv) { bv = v; best = q; }
        }
        double tmpd = ds[i][p]; ds[i][p] = ds[i][best]; ds[i][best] = tmpd;
        int tmpi = is[i][p]; is[i][p] = is[i][best]; is[i][best] = tmpi;
        kn[(size_t)b*NCG*NCG + (size_t)i*NCG + p] = (float)is[i][p];
    }
}

// ---------------- adj (written LAST; its region doubles as f64 scratch) ----------------
__global__ void k_zero_adj(float4* adj4, long n4) {
    long i = (long)blockIdx.x * blockDim.x + threadIdx.x;
    long stride = (long)gridDim.x * blockDim.x;
    float4 z; z.x = z.y = z.z = z.w = 0.f;
    for (; i < n4; i += stride) adj4[i] = z;
}

__global__ void k_bonds_adj(const int* __restrict__ bonds, int nb, float* adj) {
    int i = blockIdx.x * blockDim.x + threadIdx.x;
    if (i >= nb) return;
    int b = bonds[i*3+0], s = bonds[i*3+1], t = bonds[i*3+2];
    size_t base = (size_t)b * NN * NN;
    adj[base + (size_t)s*NN + t] = 1.f;
    adj[base + (size_t)t*NN + s] = 1.f;
}

extern "C" void kernel_launch(void* const* d_in, const int* in_sizes, int n_in,
                              void* d_out, int out_size, void* d_ws, size_t ws_size,
                              hipStream_t stream) {
    const int*   atoms  = (const int*)  d_in[0];
    const float* xyz    = (const float*)d_in[1];
    const int*   bonds  = (const int*)  d_in[2];
    const float* tau    = (const float*)d_in[3];
    const float* gum    = (const float*)d_in[4];
    const float* emb    = (const float*)d_in[5];
    const float* uW1    = (const float*)d_in[6];
    const float* ub1    = (const float*)d_in[7];
    const float* uW2    = (const float*)d_in[8];
    const float* ub2    = (const float*)d_in[9];
    const float* cgW1   = (const float*)d_in[10];
    const float* cgb1   = (const float*)d_in[11];
    const float* cgW2   = (const float*)d_in[12];
    const float* cgb2   = (const float*)d_in[13];

    float* out = (float*)d_out;

    float* o_M   = out + O_M;
    float* o_Mn  = out + O_MN;
    float* o_h   = out + O_H;
    float* o_H   = out + O_HH;
    float* o_adj = out + O_ADJ;
    float* o_cg  = out + O_CGXYZ;
    float* o_ca  = out + O_CGADJ;
    float* o_kn  = out + O_KN;

    // f64 scratch aliased over the adj output region (40MB of 64MB)
    double* scr  = (double*)o_adj;
    double* h64  = scr + S_H64;
    double* t64  = scr + S_T64;
    double* lm64 = scr + S_LM64;

    double* wsd     = (double*)d_ws;
    double* invdeg  = wsd + W_INVD;
    double* colsum  = wsd + W_COLS;
    double* cg64    = wsd + W_CG;
    int*    degcnt  = (int*)(wsd + W_DEG);

    const int nb = in_sizes[2] / 3;

    hipLaunchKernelGGL(k_zero_small, dim3(64), dim3(256), 0, stream, degcnt, colsum);
    hipLaunchKernelGGL(k_deg, dim3((nb+255)/256), dim3(256), 0, stream, bonds, nb, degcnt);
    hipLaunchKernelGGL(k_invdeg, dim3(64), dim3(256), 0, stream, degcnt, invdeg);
    hipLaunchKernelGGL(k_cgadj, dim3(256), dim3(256), 0, stream, o_ca);
    hipLaunchKernelGGL(k_emb64, dim3(2048), dim3(256), 0, stream, atoms, emb, h64);

    for (int l = 0; l < NCONV; ++l) {
        hipLaunchKernelGGL((k_gemm64<128,true>), dim3(512), dim3(256), 0, stream,
                           h64, uW1 + (size_t)l*FF*FF, ub1 + (size_t)l*FF, t64);
        hipLaunchKernelGGL((k_gemm64<128,false>), dim3(512), dim3(256), 0, stream,
                           t64, uW2 + (size_t)l*FF*FF, ub2 + (size_t)l*FF, t64);
        hipLaunchKernelGGL(k_scatter64, dim3((nb*(FF/4)+255)/256), dim3(256), 0, stream,
                           t64, invdeg, bonds, nb, h64);
    }

    hipLaunchKernelGGL((k_gemm64<128,true>), dim3(512), dim3(256), 0, stream,
                       h64, cgW1, cgb1, t64);
    hipLaunchKernelGGL((k_gemm64<64,false>), dim3(512), dim3(256), 0, stream,
                       t64, cgW2, cgb2, lm64);

    hipLaunchKernelGGL(k_softmax64, dim3(4096), dim3(256), 0, stream,
                       lm64, gum, tau, o_M, colsum);
    hipLaunchKernelGGL(k_mnorm_out, dim3(4096), dim3(256), 0, stream, lm64, colsum, o_Mn);
    hipLaunchKernelGGL(k_hout, dim3(8192), dim3(256), 0, stream, h64, o_h);
    hipLaunchKernelGGL(k_H64, dim3(128), dim3(256), 0, stream, lm64, colsum, h64, o_H);
    hipLaunchKernelGGL(k_cgxyz64, dim3(16), dim3(192), 0, stream, lm64, colsum, xyz, cg64, o_cg);
    hipLaunchKernelGGL(k_knbrs64, dim3(16), dim3(64), 0, stream, cg64, o_kn);

    // adj LAST: its region was scratch until here
    hipLaunchKernelGGL(k_zero_adj, dim3(4096), dim3(256), 0, stream,
                       (float4*)o_adj, (long)BB*NN*NN/4);
    hipLaunchKernelGGL(k_bonds_adj, dim3((nb+255)/256), dim3(256), 0, stream,
                       bonds, nb, o_adj);
}

// Round 3
// 352.668 us; speedup vs baseline: 2.3716x; 2.3716x over previous
//
#include <hip/hip_runtime.h>
#include <hip/hip_bf16.h>
#include <math.h>

// Problem constants
#define BB 16
#define NN 1024
#define FF 128
#define NCG 64
#define NCONV 3
#define CAP 8

// ---- output layout (floats) ----
static const size_t O_M     = 0;
static const size_t O_MN    = (size_t)BB*NN*NCG;              // 1048576
static const size_t O_H     = O_MN  + (size_t)BB*NN*NCG;      // 2097152
static const size_t O_HH    = O_H   + (size_t)BB*NN*FF;       // 4194304
static const size_t O_ADJ   = O_HH  + (size_t)BB*NCG*FF;      // 4325376
static const size_t O_CGXYZ = O_ADJ + (size_t)BB*NN*NN;       // 21102592
static const size_t O_CGADJ = O_CGXYZ + (size_t)BB*NCG*3;     // 21105664
static const size_t O_KN    = O_CGADJ + (size_t)BB*NCG*NCG;   // 21171200

// f64 scratch aliased into adj output region (written last). adj = 8388608 doubles.
static const size_t S_H64  = 0;                                // [B*N*F]
static const size_t S_T64  = (size_t)BB*NN*FF;                 // 2097152
static const size_t S_LM64 = S_T64 + (size_t)BB*NN*FF;         // 4194304
static const size_t S_HP   = S_LM64 + (size_t)BB*NN*NCG;       // 5242880 : 8 chunks x [B*NCG*F]
static const size_t S_CGP  = S_HP + 8*(size_t)BB*NCG*FF;       // 6291456 : 8 x [B*NCG*3]
static const size_t S_NBR  = S_CGP + 8*(size_t)BB*NCG*3;       // 6316032 : B*N*CAP ints
// end: 6316032 + 65536 = 6381568 < 8388608  OK

// ---- ws layout (doubles) ----
static const size_t W_INVD = 0;                                // [B*N]
static const size_t W_COLS = (size_t)BB*NN;                    // [B*NCG]
static const size_t W_CG64 = W_COLS + (size_t)BB*NCG;          // [B*NCG*3]
static const size_t W_CNT  = W_CG64 + (size_t)BB*NCG*3;        // B*N ints

// ---------------- init ----------------
__global__ void k_zero(int* cnt, double* colsum) {
    int i = blockIdx.x * blockDim.x + threadIdx.x;
    if (i < BB*NN) cnt[i] = 0;
    if (i < BB*NCG) colsum[i] = 0.0;
}

__global__ void k_build_nbr(const int* __restrict__ bonds, int nb, int* cnt, int* nbr) {
    int i = blockIdx.x * blockDim.x + threadIdx.x;
    if (i >= nb) return;
    int b = bonds[i*3+0], s = bonds[i*3+1], t = bonds[i*3+2];
    int ns = b*NN + s, nt = b*NN + t;
    int p = atomicAdd(&cnt[ns], 1);
    if (p < CAP) nbr[(size_t)ns*CAP + p] = nt;
    int q = atomicAdd(&cnt[nt], 1);
    if (q < CAP) nbr[(size_t)nt*CAP + q] = ns;
}

__global__ void k_invdeg(const int* __restrict__ cnt, double* invdeg) {
    int i = blockIdx.x * blockDim.x + threadIdx.x;
    if (i >= BB*NN) return;
    int d = cnt[i];
    invdeg[i] = d > 0 ? 1.0 / (double)d : 0.0;
}

__global__ void k_cgadj(float* cgadj) {
    int idx = blockIdx.x * blockDim.x + threadIdx.x;
    if (idx >= BB*NCG*NCG) return;
    int i = (idx / NCG) % NCG, j = idx % NCG;
    cgadj[idx] = (i == j) ? 0.f : 1.f;
}

__global__ void k_emb64(const int* __restrict__ atoms, const float* __restrict__ emb,
                        double* __restrict__ h) {
    int idx = blockIdx.x * blockDim.x + threadIdx.x;
    if (idx >= BB*NN*(FF/4)) return;
    int n = idx / (FF/4), f4 = idx % (FF/4);
    int a = atoms[n];
    const float4 v = *reinterpret_cast<const float4*>(&emb[(size_t)a*FF + f4*4]);
    double* hp = &h[(size_t)n*FF + f4*4];
    hp[0] = (double)v.x; hp[1] = (double)v.y; hp[2] = (double)v.z; hp[3] = (double)v.w;
}

// ---------------- f64 GEMM: out = act(in @ W + b), K=128 ----------------
// 64-row tiles, KC=32 chunks. Thread tile: RPT rows x 8 cols (cols interleaved
// as c = tc*2 + g*(COUT/4) so LDS W-reads and stores are conflict-free b128).
template<int COUT, bool TANH>
__global__ __launch_bounds__(256) void k_gemm64(const double* __restrict__ in,
                                                const float* __restrict__ W,
                                                const float* __restrict__ bias,
                                                double* __restrict__ out) {
    constexpr int K = 128, ROWS = 64, KC = 32;
    constexpr int ASTR = KC + 2;          // pad: breaks 4-way bank conflict on A reads
    constexpr int CT = COUT / 8;          // 16 or 8 col-threads
    constexpr int RT = 256 / CT;          // 16 or 32 row-threads
    constexpr int RPT = ROWS / RT;        // 4 or 2 rows/thread
    constexpr int GS = COUT / 4;          // col-group stride
    __shared__ double As[ROWS * ASTR];    // 17 KB
    __shared__ double Ws[KC * COUT];      // 32 or 16 KB
    const int tid = threadIdx.x;
    const size_t row0 = (size_t)blockIdx.x * ROWS;
    const int tc = tid % CT, tr = tid / CT;
    const int r0 = tr * RPT;

    double acc[RPT][8];
    #pragma unroll
    for (int i = 0; i < RPT; ++i)
        #pragma unroll
        for (int j = 0; j < 8; ++j) acc[i][j] = 0.0;

    const double2* in2 = reinterpret_cast<const double2*>(in + row0 * K);

    for (int kc = 0; kc < K; kc += KC) {
        __syncthreads();
        // stage A chunk: 64 x 32 doubles
        #pragma unroll
        for (int i = 0; i < 4; ++i) {
            int q = tid + i*256;               // 1024 double2
            int row = q >> 4, c2 = q & 15;
            *reinterpret_cast<double2*>(&As[row*ASTR + c2*2]) = in2[row*64 + (kc>>1) + c2];
        }
        // stage W chunk (f32 -> f64): KC x COUT
        {
            const float4* Wg = reinterpret_cast<const float4*>(W + (size_t)kc * COUT);
            #pragma unroll
            for (int i = 0; i < KC*COUT/4/256; ++i) {
                int q = tid + i*256;
                float4 w = Wg[q];
                Ws[q*4+0] = (double)w.x; Ws[q*4+1] = (double)w.y;
                Ws[q*4+2] = (double)w.z; Ws[q*4+3] = (double)w.w;
            }
        }
        __syncthreads();
        #pragma unroll
        for (int kk = 0; kk < KC; ++kk) {
            double a_[RPT];
            #pragma unroll
            for (int i = 0; i < RPT; ++i) a_[i] = As[(r0+i)*ASTR + kk];
            const double2* wb = reinterpret_cast<const double2*>(&Ws[kk*COUT]);
            double2 wg[4];
            #pragma unroll
            for (int g = 0; g < 4; ++g) wg[g] = wb[tc + g*CT];
            #pragma unroll
            for (int i = 0; i < RPT; ++i)
                #pragma unroll
                for (int g = 0; g < 4; ++g) {
                    acc[i][g*2+0] += a_[i] * wg[g].x;
                    acc[i][g*2+1] += a_[i] * wg[g].y;
                }
        }
    }

    double bv[8];
    #pragma unroll
    for (int g = 0; g < 4; ++g) {
        bv[g*2+0] = (double)bias[tc*2 + g*GS + 0];
        bv[g*2+1] = (double)bias[tc*2 + g*GS + 1];
    }
    #pragma unroll
    for (int i = 0; i < RPT; ++i) {
        double2* op = reinterpret_cast<double2*>(out + (row0 + r0 + i) * COUT);
        #pragma unroll
        for (int g = 0; g < 4; ++g) {
            double v0 = acc[i][g*2+0] + bv[g*2+0];
            double v1 = acc[i][g*2+1] + bv[g*2+1];
            if (TANH) { v0 = tanh(v0); v1 = tanh(v1); }
            double2 o; o.x = v0; o.y = v1;
            op[tc + g*CT] = o;
        }
    }
}

// ---------------- gather: h[node,:] += invdeg[node] * sum_nbr ch[nbr,:] ----------------
template<bool WRITE_F32>
__global__ void k_gather(const double* __restrict__ ch, const double* __restrict__ invdeg,
                         const int* __restrict__ nbr, const int* __restrict__ cnt,
                         double* __restrict__ h, float* __restrict__ hout) {
    int idx = blockIdx.x * blockDim.x + threadIdx.x;
    if (idx >= BB*NN*(FF/4)) return;
    int node = idx >> 5, f4 = idx & 31;
    int c = cnt[node];
    double2 s0; s0.x = 0.0; s0.y = 0.0;
    double2 s1 = s0;
    for (int q = 0; q < c; ++q) {
        int nb = nbr[(size_t)node*CAP + q];
        const double2* cp = reinterpret_cast<const double2*>(ch + (size_t)nb*FF + f4*4);
        double2 a = cp[0], b2 = cp[1];
        s0.x += a.x; s0.y += a.y; s1.x += b2.x; s1.y += b2.y;
    }
    double w = invdeg[node];
    double2* hp = reinterpret_cast<double2*>(h + (size_t)node*FF + f4*4);
    double2 h0 = hp[0], h1 = hp[1];
    h0.x += s0.x*w; h0.y += s0.y*w; h1.x += s1.x*w; h1.y += s1.y*w;
    hp[0] = h0; hp[1] = h1;
    if (WRITE_F32) {
        float4 o; o.x = (float)h0.x; o.y = (float)h0.y; o.z = (float)h1.x; o.w = (float)h1.y;
        *reinterpret_cast<float4*>(&hout[(size_t)node*FF + f4*4]) = o;
    }
}

// ---------------- gumbel softmax (f64, in-place logits->M) ----------------
__global__ void k_softmax64(double* __restrict__ lm, const float* __restrict__ gum,
                            const float* __restrict__ tau_p, float* __restrict__ M_out,
                            double* __restrict__ colsum) {
    int row = blockIdx.x * 4 + threadIdx.x / 64;
    int lane = threadIdx.x & 63;
    double tau = (double)(*tau_p);
    double u = (double)gum[(size_t)row*NCG + lane];
    double g = -log(-log(u));
    double v = (lm[(size_t)row*NCG + lane] + g) / tau;
    double m = v;
    #pragma unroll
    for (int off = 32; off; off >>= 1) m = fmax(m, __shfl_xor(m, off));
    double e = exp(v - m);
    double s = e;
    #pragma unroll
    for (int off = 32; off; off >>= 1) s += __shfl_xor(s, off);
    double mv = e / s;
    lm[(size_t)row*NCG + lane] = mv;
    M_out[(size_t)row*NCG + lane] = (float)mv;
    atomicAdd(&colsum[(row >> 10) * NCG + lane], mv);
}

__global__ void k_mnorm_out(const double* __restrict__ M, const double* __restrict__ colsum,
                            float* __restrict__ Mn) {
    size_t i = (size_t)blockIdx.x * blockDim.x + threadIdx.x;
    if (i >= (size_t)BB*NN*NCG) return;
    size_t b = i >> 16;
    int j = (int)(i & 63);
    Mn[i] = (float)(M[i] / colsum[b*NCG + j]);
}

// ---------------- H partials: Hp[ch][b][j][f] = sum_{n in chunk} M[b,n,j] h[b,n,f] ----------------
__global__ __launch_bounds__(256) void k_Hpart(const double* __restrict__ M,
                                               const double* __restrict__ h,
                                               double* __restrict__ Hp) {
    __shared__ double Ms[32*NCG];   // 16 KB
    __shared__ double hs[32*FF];    // 32 KB
    const int b = blockIdx.x, ch = blockIdx.y;
    const int tid = threadIdx.x;
    const int tc = tid % 32, tr = tid / 32;   // tc -> f pairs, tr -> j pairs
    const double2* M2 = reinterpret_cast<const double2*>(M + (size_t)b*NN*NCG);
    const double2* h2 = reinterpret_cast<const double2*>(h + (size_t)b*NN*FF);
    double2* Ms2 = reinterpret_cast<double2*>(Ms);
    double2* hs2 = reinterpret_cast<double2*>(hs);

    double acc[8][4];   // j: tr*2 + gj*16 + pj ; f: tc*2 + gf*64 + pf
    #pragma unroll
    for (int i = 0; i < 8; ++i)
        #pragma unroll
        for (int j = 0; j < 4; ++j) acc[i][j] = 0.0;

    for (int s = 0; s < 4; ++s) {
        const int n0 = ch*128 + s*32;
        __syncthreads();
        #pragma unroll
        for (int i = 0; i < 4; ++i) Ms2[tid + i*256] = M2[n0*32 + tid + i*256];
        #pragma unroll
        for (int i = 0; i < 8; ++i) hs2[tid + i*256] = h2[n0*64 + tid + i*256];
        __syncthreads();
        for (int n = 0; n < 32; ++n) {
            double2 hv0 = hs2[n*64 + tc];        // f = tc*2, tc*2+1
            double2 hv1 = hs2[n*64 + 32 + tc];   // f = 64 + tc*2, +1
            double2 m0 = Ms2[n*32 + tr];         // j = tr*2, tr*2+1
            double2 m1 = Ms2[n*32 + 8 + tr];
            double2 m2 = Ms2[n*32 + 16 + tr];
            double2 m3 = Ms2[n*32 + 24 + tr];
            double mj[8] = {m0.x, m0.y, m1.x, m1.y, m2.x, m2.y, m3.x, m3.y};
            #pragma unroll
            for (int jj = 0; jj < 8; ++jj) {
                acc[jj][0] += mj[jj]*hv0.x; acc[jj][1] += mj[jj]*hv0.y;
                acc[jj][2] += mj[jj]*hv1.x; acc[jj][3] += mj[jj]*hv1.y;
            }
        }
    }
    double* Ho = Hp + ((size_t)ch*BB + b) * NCG * FF;
    #pragma unroll
    for (int gj = 0; gj < 4; ++gj)
        #pragma unroll
        for (int pj = 0; pj < 2; ++pj) {
            int j = tr*2 + gj*16 + pj;
            int jj = gj*2 + pj;
            double2* op = reinterpret_cast<double2*>(Ho + (size_t)j*FF);
            double2 o0; o0.x = acc[jj][0]; o0.y = acc[jj][1];
            double2 o1; o1.x = acc[jj][2]; o1.y = acc[jj][3];
            op[tc] = o0; op[32 + tc] = o1;
        }
}

__global__ void k_Hfin(const double* __restrict__ Hp, const double* __restrict__ colsum,
                       float* __restrict__ H) {
    int idx = blockIdx.x * blockDim.x + threadIdx.x;
    if (idx >= BB*NCG*FF) return;
    int b = idx / (NCG*FF);
    int j = (idx / FF) % NCG;
    double s = 0.0;
    #pragma unroll
    for (int c = 0; c < 8; ++c) s += Hp[((size_t)c*BB + b)*NCG*FF + (idx % (NCG*FF))];
    H[idx] = (float)(s / colsum[b*NCG + j]);
}

// ---------------- cg partials ----------------
__global__ __launch_bounds__(192) void k_cgpart(const double* __restrict__ M,
                                                const float* __restrict__ xyz,
                                                double* __restrict__ cgp) {
    __shared__ double Ms[32*NCG];   // 16 KB
    __shared__ double xs[32*3];
    const int b = blockIdx.x, ch = blockIdx.y;
    const int tid = threadIdx.x;     // 192 = (j, d)
    const int j = tid / 3, d = tid % 3;
    const double2* M2 = reinterpret_cast<const double2*>(M + (size_t)b*NN*NCG);
    double2* Ms2 = reinterpret_cast<double2*>(Ms);
    const float* xb = xyz + (size_t)b*NN*3;
    double acc = 0.0;
    for (int s = 0; s < 4; ++s) {
        const int n0 = ch*128 + s*32;
        __syncthreads();
        for (int q = tid; q < 1024; q += 192) Ms2[q] = M2[n0*32 + q];
        for (int q = tid; q < 96; q += 192) xs[q] = (double)xb[n0*3 + q];
        __syncthreads();
        for (int n = 0; n < 32; ++n)
            acc += Ms[n*NCG + j] * xs[n*3 + d];
    }
    cgp[((size_t)ch*BB + b)*NCG*3 + tid] = acc;
}

__global__ void k_cgfin(const double* __restrict__ cgp, const double* __restrict__ colsum,
                        double* __restrict__ cg64, float* __restrict__ cg) {
    int idx = blockIdx.x * blockDim.x + threadIdx.x;
    if (idx >= BB*NCG*3) return;
    int b = idx / (NCG*3);
    int r = idx % (NCG*3);
    int j = r / 3;
    double s = 0.0;
    #pragma unroll
    for (int c = 0; c < 8; ++c) s += cgp[((size_t)c*BB + b)*NCG*3 + r];
    double v = s / colsum[b*NCG + j];
    cg64[idx] = v;
    cg[idx] = (float)v;
}

// ---------------- knbrs: rank-count argsort over squared distances ----------------
__global__ __launch_bounds__(1024) void k_knbrs(const double* __restrict__ cg,
                                                float* __restrict__ kn) {
    __shared__ double cs[NCG*3];
    const int b = blockIdx.x;
    const int tid = threadIdx.x;
    const int i = blockIdx.y * 16 + tid / 64;
    const int j = tid & 63;
    if (tid < NCG*3) cs[tid] = cg[(size_t)b*NCG*3 + tid];
    __syncthreads();
    double xi = cs[i*3+0], yi = cs[i*3+1], zi = cs[i*3+2];
    double dxj = xi - cs[j*3+0], dyj = yi - cs[j*3+1], dzj = zi - cs[j*3+2];
    double d2j = dxj*dxj + dyj*dyj + dzj*dzj;
    int rank = 0;
    for (int k = 0; k < NCG; ++k) {
        double dx = xi - cs[k*3+0], dy = yi - cs[k*3+1], dz = zi - cs[k*3+2];
        double d2k = dx*dx + dy*dy + dz*dz;
        rank += (d2k < d2j) || (d2k == d2j && k < j);
    }
    kn[(size_t)b*NCG*NCG + (size_t)i*NCG + rank] = (float)j;
}

// ---------------- adj (written LAST; region doubles as f64 scratch) ----------------
__global__ void k_zero_adj(float4* adj4, long n4) {
    long i = (long)blockIdx.x * blockDim.x + threadIdx.x;
    long stride = (long)gridDim.x * blockDim.x;
    float4 z; z.x = z.y = z.z = z.w = 0.f;
    for (; i < n4; i += stride) adj4[i] = z;
}

__global__ void k_bonds_adj(const int* __restrict__ bonds, int nb, float* adj) {
    int i = blockIdx.x * blockDim.x + threadIdx.x;
    if (i >= nb) return;
    int b = bonds[i*3+0], s = bonds[i*3+1], t = bonds[i*3+2];
    size_t base = (size_t)b * NN * NN;
    adj[base + (size_t)s*NN + t] = 1.f;
    adj[base + (size_t)t*NN + s] = 1.f;
}

extern "C" void kernel_launch(void* const* d_in, const int* in_sizes, int n_in,
                              void* d_out, int out_size, void* d_ws, size_t ws_size,
                              hipStream_t stream) {
    const int*   atoms  = (const int*)  d_in[0];
    const float* xyz    = (const float*)d_in[1];
    const int*   bonds  = (const int*)  d_in[2];
    const float* tau    = (const float*)d_in[3];
    const float* gum    = (const float*)d_in[4];
    const float* emb    = (const float*)d_in[5];
    const float* uW1    = (const float*)d_in[6];
    const float* ub1    = (const float*)d_in[7];
    const float* uW2    = (const float*)d_in[8];
    const float* ub2    = (const float*)d_in[9];
    const float* cgW1   = (const float*)d_in[10];
    const float* cgb1   = (const float*)d_in[11];
    const float* cgW2   = (const float*)d_in[12];
    const float* cgb2   = (const float*)d_in[13];

    float* out = (float*)d_out;
    float* o_M   = out + O_M;
    float* o_Mn  = out + O_MN;
    float* o_h   = out + O_H;
    float* o_H   = out + O_HH;
    float* o_adj = out + O_ADJ;
    float* o_cg  = out + O_CGXYZ;
    float* o_ca  = out + O_CGADJ;
    float* o_kn  = out + O_KN;

    double* scr  = (double*)o_adj;
    double* h64  = scr + S_H64;
    double* t64  = scr + S_T64;
    double* lm64 = scr + S_LM64;
    double* Hp   = scr + S_HP;
    double* cgp  = scr + S_CGP;
    int*    nbr  = (int*)(scr + S_NBR);

    double* wsd    = (double*)d_ws;
    double* invdeg = wsd + W_INVD;
    double* colsum = wsd + W_COLS;
    double* cg64   = wsd + W_CG64;
    int*    cnt    = (int*)(wsd + W_CNT);

    const int nb = in_sizes[2] / 3;

    hipLaunchKernelGGL(k_zero, dim3(64), dim3(256), 0, stream, cnt, colsum);
    hipLaunchKernelGGL(k_build_nbr, dim3((nb+255)/256), dim3(256), 0, stream,
                       bonds, nb, cnt, nbr);
    hipLaunchKernelGGL(k_invdeg, dim3(64), dim3(256), 0, stream, cnt, invdeg);
    hipLaunchKernelGGL(k_cgadj, dim3(256), dim3(256), 0, stream, o_ca);
    hipLaunchKernelGGL(k_emb64, dim3(2048), dim3(256), 0, stream, atoms, emb, h64);

    for (int l = 0; l < NCONV; ++l) {
        hipLaunchKernelGGL((k_gemm64<128,true>), dim3(256), dim3(256), 0, stream,
                           h64, uW1 + (size_t)l*FF*FF, ub1 + (size_t)l*FF, t64);
        hipLaunchKernelGGL((k_gemm64<128,false>), dim3(256), dim3(256), 0, stream,
                           t64, uW2 + (size_t)l*FF*FF, ub2 + (size_t)l*FF, t64);
        if (l < NCONV-1)
            hipLaunchKernelGGL((k_gather<false>), dim3(2048), dim3(256), 0, stream,
                               t64, invdeg, nbr, cnt, h64, o_h);
        else
            hipLaunchKernelGGL((k_gather<true>), dim3(2048), dim3(256), 0, stream,
                               t64, invdeg, nbr, cnt, h64, o_h);
    }

    hipLaunchKernelGGL((k_gemm64<128,true>), dim3(256), dim3(256), 0, stream,
                       h64, cgW1, cgb1, t64);
    hipLaunchKernelGGL((k_gemm64<64,false>), dim3(256), dim3(256), 0, stream,
                       t64, cgW2, cgb2, lm64);

    hipLaunchKernelGGL(k_softmax64, dim3(4096), dim3(256), 0, stream,
                       lm64, gum, tau, o_M, colsum);
    hipLaunchKernelGGL(k_mnorm_out, dim3(4096), dim3(256), 0, stream, lm64, colsum, o_Mn);
    hipLaunchKernelGGL(k_Hpart, dim3(BB, 8), dim3(256), 0, stream, lm64, h64, Hp);
    hipLaunchKernelGGL(k_Hfin, dim3(512), dim3(256), 0, stream, Hp, colsum, o_H);
    hipLaunchKernelGGL(k_cgpart, dim3(BB, 8), dim3(192), 0, stream, lm64, xyz, cgp);
    hipLaunchKernelGGL(k_cgfin, dim3(12), dim3(256), 0, stream, cgp, colsum, cg64, o_cg);
    hipLaunchKernelGGL(k_knbrs, dim3(BB, 4), dim3(1024), 0, stream, cg64, o_kn);

    // adj LAST: its region was scratch until here
    hipLaunchKernelGGL(k_zero_adj, dim3(4096), dim3(256), 0, stream,
                       (float4*)o_adj, (long)BB*NN*NN/4);
    hipLaunchKernelGGL(k_bonds_adj, dim3((nb+255)/256), dim3(256), 0, stream,
                       bonds, nb, o_adj);
}